// Round 1
// baseline (566.474 us; speedup 1.0000x reference)
//
#include <hip/hip_runtime.h>

#define NEG_SLOPE 0.2f

static __device__ __forceinline__ float lrelu(float x) { return x > 0.f ? x : NEG_SLOPE * x; }

// ---------------- CSR build ----------------

__global__ void deg_count(const int* __restrict__ dst, int* __restrict__ deg, int ne) {
    int i = blockIdx.x * 256 + threadIdx.x;
    if (i < ne) atomicAdd(&deg[dst[i]], 1);
}

__global__ void scan_partial(const int* __restrict__ deg, int* __restrict__ partial, int n) {
    int i = blockIdx.x * 256 + threadIdx.x;
    int v = (i < n) ? deg[i] : 0;
    #pragma unroll
    for (int off = 32; off >= 1; off >>= 1) v += __shfl_xor(v, off, 64);
    __shared__ int ws[4];
    int lane = threadIdx.x & 63, wid = threadIdx.x >> 6;
    if (lane == 0) ws[wid] = v;
    __syncthreads();
    if (threadIdx.x == 0) partial[blockIdx.x] = ws[0] + ws[1] + ws[2] + ws[3];
}

// single block, 512 threads; exclusive scan of nb (<=512) block partials
__global__ void scan_offsets(const int* __restrict__ partial, int* __restrict__ chunkoff, int nb) {
    int t = threadIdx.x;
    int v = (t < nb) ? partial[t] : 0;
    int lane = t & 63, wid = t >> 6;
    int incl = v;
    #pragma unroll
    for (int off = 1; off < 64; off <<= 1) {
        int u = __shfl_up(incl, off, 64);
        if (lane >= off) incl += u;
    }
    __shared__ int ws[8];
    if (lane == 63) ws[wid] = incl;
    __syncthreads();
    if (t < 8) {
        int s = ws[t];
        #pragma unroll
        for (int off = 1; off < 8; off <<= 1) {
            int u = __shfl_up(s, off, 64);
            if (t >= off) s += u;
        }
        ws[t] = s;  // inclusive scan of wave sums
    }
    __syncthreads();
    int excl = incl - v + (wid > 0 ? ws[wid - 1] : 0);
    if (t < nb) chunkoff[t] = excl;
}

__global__ void scan_final(const int* __restrict__ deg, const int* __restrict__ chunkoff,
                           int* __restrict__ rowstart, int* __restrict__ cursor, int n) {
    int i = blockIdx.x * 256 + threadIdx.x;
    int v = (i < n) ? deg[i] : 0;
    int lane = threadIdx.x & 63, wid = threadIdx.x >> 6;
    int incl = v;
    #pragma unroll
    for (int off = 1; off < 64; off <<= 1) {
        int u = __shfl_up(incl, off, 64);
        if (lane >= off) incl += u;
    }
    __shared__ int ws[4];
    if (lane == 63) ws[wid] = incl;
    __syncthreads();
    if (threadIdx.x < 4) {
        int s = ws[threadIdx.x];
        #pragma unroll
        for (int off = 1; off < 4; off <<= 1) {
            int u = __shfl_up(s, off, 64);
            if (threadIdx.x >= off) s += u;
        }
        ws[threadIdx.x] = s;
    }
    __syncthreads();
    int excl = incl - v + (wid > 0 ? ws[wid - 1] : 0) + chunkoff[blockIdx.x];
    if (i < n) { rowstart[i] = excl; cursor[i] = excl; }
}

__global__ void csr_scatter(const int* __restrict__ src, const int* __restrict__ dst,
                            int* __restrict__ cursor, int* __restrict__ csrc, int ne) {
    int i = blockIdx.x * 256 + threadIdx.x;
    if (i < ne) {
        int pos = atomicAdd(&cursor[dst[i]], 1);
        csrc[pos] = src[i];
    }
}

// ---------------- Layer 1: h1 = x @ W1 (+ att scalars) ----------------
// block = 256 thr (4 waves), 32 nodes/block; lane = output column (HID=64)

__global__ __launch_bounds__(256) void gemm1(const float* __restrict__ x, const float* __restrict__ W1,
                                             const float* __restrict__ asrc, const float* __restrict__ adst,
                                             float* __restrict__ h, float* __restrict__ es,
                                             float* __restrict__ ed, int n) {
    __shared__ float Wl[128][64];   // 32 KB
    __shared__ float xl[32][128];   // 16 KB
    int tid = threadIdx.x;
    for (int i = tid; i < 128 * 64; i += 256) Wl[i >> 6][i & 63] = W1[i];
    int base = blockIdx.x * 32;
    for (int i = tid; i < 32 * 128; i += 256) {
        int r = i >> 7, c = i & 127;
        int nidx = base + r;
        xl[r][c] = (nidx < n) ? x[(size_t)nidx * 128 + c] : 0.f;
    }
    __syncthreads();
    int lane = tid & 63, wid = tid >> 6;
    float as_ = asrc[lane], ad_ = adst[lane];
    for (int r = wid; r < 32; r += 4) {
        int nidx = base + r;
        if (nidx >= n) break;
        float acc = 0.f;
        #pragma unroll
        for (int k = 0; k < 128; ++k) acc = fmaf(xl[r][k], Wl[k][lane], acc);
        h[(size_t)nidx * 64 + lane] = acc;
        float s = acc * as_, d = acc * ad_;
        #pragma unroll
        for (int off = 32; off >= 1; off >>= 1) {
            s += __shfl_xor(s, off, 64);
            d += __shfl_xor(d, off, 64);
        }
        if (lane == 0) { es[nidx] = s; ed[nidx] = d; }
    }
}

// ---------------- Layer 1 aggregation: one wave per dst node, online softmax ----------------

__global__ __launch_bounds__(256) void agg1(const float* __restrict__ h, const float* __restrict__ es,
                                            const float* __restrict__ ed, const float* __restrict__ b1,
                                            const int* __restrict__ rowstart, const int* __restrict__ deg,
                                            const int* __restrict__ csrc, float* __restrict__ out, int n) {
    int wid = threadIdx.x >> 6, lane = threadIdx.x & 63;
    int node = blockIdx.x * 4 + wid;
    if (node >= n) return;
    float edn = ed[node];
    float e0 = lrelu(es[node] + edn);   // self-loop
    float m = e0, z = 1.0f;
    float acc = h[(size_t)node * 64 + lane];
    int s0 = rowstart[node], cnt = deg[node];
    for (int i = 0; i < cnt; ++i) {
        int s = csrc[s0 + i];
        float e = lrelu(es[s] + edn);
        float hv = h[(size_t)s * 64 + lane];
        if (e <= m) {                       // wave-uniform branch
            float w = __expf(e - m);
            z += w;
            acc = fmaf(hv, w, acc);
        } else {
            float c = __expf(m - e);
            z = fmaf(z, c, 1.0f);
            acc = fmaf(acc, c, hv);
            m = e;
        }
    }
    float o = acc / z + b1[lane];
    out[(size_t)node * 64 + lane] = o > 0.f ? o : 0.f;   // fused ReLU
}

// ---------------- Layer 2: h2 = hr @ W2 (+ att scalars) ----------------
// block = 256 thr; wave = 4 nodes x 16 cols

__global__ __launch_bounds__(256) void gemm2(const float* __restrict__ hin, const float* __restrict__ W2,
                                             const float* __restrict__ asrc, const float* __restrict__ adst,
                                             float* __restrict__ h2, float* __restrict__ es,
                                             float* __restrict__ ed, int n) {
    __shared__ float Wl[64][16];   // 4 KB
    __shared__ float xl[16][64];   // 4 KB
    int tid = threadIdx.x;
    for (int i = tid; i < 64 * 16; i += 256) Wl[i >> 4][i & 15] = W2[i];
    int base = blockIdx.x * 16;
    for (int i = tid; i < 16 * 64; i += 256) {
        int r = i >> 6, c = i & 63;
        int nidx = base + r;
        xl[r][c] = (nidx < n) ? hin[(size_t)nidx * 64 + c] : 0.f;
    }
    __syncthreads();
    int lane = tid & 63, wid = tid >> 6;
    int sub = lane >> 4, j = lane & 15;
    int r = wid * 4 + sub;
    int nidx = base + r;
    if (nidx < n) {
        float acc = 0.f;
        #pragma unroll
        for (int k = 0; k < 64; ++k) acc = fmaf(xl[r][k], Wl[k][j], acc);
        h2[(size_t)nidx * 16 + j] = acc;
        float s = acc * asrc[j], d = acc * adst[j];
        #pragma unroll
        for (int off = 8; off >= 1; off >>= 1) {
            s += __shfl_xor(s, off, 64);
            d += __shfl_xor(d, off, 64);
        }
        if (j == 0) { es[nidx] = s; ed[nidx] = d; }
    }
}

// ---------------- Layer 2 aggregation + bias + log_softmax ----------------
// one wave per node; 4 subgroups of 16 lanes process 4 edges in parallel,
// online-softmax states merged by shuffle at the end.

__global__ __launch_bounds__(256) void agg2(const float* __restrict__ h, const float* __restrict__ es,
                                            const float* __restrict__ ed, const float* __restrict__ b2,
                                            const int* __restrict__ rowstart, const int* __restrict__ deg,
                                            const int* __restrict__ csrc, float* __restrict__ out, int n) {
    int wid = threadIdx.x >> 6, lane = threadIdx.x & 63;
    int node = blockIdx.x * 4 + wid;
    if (node >= n) return;
    int sub = lane >> 4, j = lane & 15;
    float edn = ed[node];
    int s0 = rowstart[node], cnt = deg[node];
    int total = cnt + 1;                       // virtual edge 0 = self-loop
    float m = -1e30f, z = 0.f, acc = 0.f;
    for (int i = sub; i < total; i += 4) {
        int s = (i == 0) ? node : csrc[s0 + i - 1];
        float e = lrelu(es[s] + edn);
        float hv = h[(size_t)s * 16 + j];
        if (e <= m) {
            float w = __expf(e - m);
            z += w;
            acc = fmaf(hv, w, acc);
        } else {
            float c = __expf(m - e);
            z = fmaf(z, c, 1.0f);
            acc = fmaf(acc, c, hv);
            m = e;
        }
    }
    // merge the 4 subgroup states (offsets 16 then 32)
    #pragma unroll
    for (int off = 16; off <= 32; off <<= 1) {
        float mo = __shfl_xor(m, off, 64);
        float zo = __shfl_xor(z, off, 64);
        float ao = __shfl_xor(acc, off, 64);
        float mn = fmaxf(m, mo);
        float c0 = __expf(m - mn), c1 = __expf(mo - mn);
        z = z * c0 + zo * c1;
        acc = acc * c0 + ao * c1;
        m = mn;
    }
    float val = acc / z + b2[j];
    // log_softmax over the 16 classes (within each 16-lane subgroup)
    float mx = val;
    #pragma unroll
    for (int off = 8; off >= 1; off >>= 1) mx = fmaxf(mx, __shfl_xor(mx, off, 64));
    float ex = __expf(val - mx);
    float se = ex;
    #pragma unroll
    for (int off = 8; off >= 1; off >>= 1) se += __shfl_xor(se, off, 64);
    float res = val - mx - __logf(se);
    if (sub == 0) out[(size_t)node * 16 + j] = res;
}

// ---------------- launch ----------------

extern "C" void kernel_launch(void* const* d_in, const int* in_sizes, int n_in,
                              void* d_out, int out_size, void* d_ws, size_t ws_size,
                              hipStream_t stream) {
    const float* x   = (const float*)d_in[0];
    const int*   ei  = (const int*)d_in[1];
    const float* W1  = (const float*)d_in[2];
    const float* as1 = (const float*)d_in[3];
    const float* ad1 = (const float*)d_in[4];
    const float* b1  = (const float*)d_in[5];
    const float* W2  = (const float*)d_in[6];
    const float* as2 = (const float*)d_in[7];
    const float* ad2 = (const float*)d_in[8];
    const float* b2  = (const float*)d_in[9];
    int n  = in_sizes[0] / 128;
    int ne = in_sizes[1] / 2;
    const int* srcv = ei;
    const int* dstv = ei + ne;

    char* ws = (char*)d_ws;
    size_t off = 0;
    auto alloc = [&](size_t bytes) -> void* {
        void* p = ws + off;
        off = (off + bytes + 255) & ~(size_t)255;
        return p;
    };
    float* h1   = (float*)alloc((size_t)n * 64 * 4);
    float* hr   = (float*)alloc((size_t)n * 64 * 4);
    float* h2   = (float*)alloc((size_t)n * 16 * 4);
    float* es1  = (float*)alloc((size_t)n * 4);
    float* ed1  = (float*)alloc((size_t)n * 4);
    float* es2  = (float*)alloc((size_t)n * 4);
    float* ed2  = (float*)alloc((size_t)n * 4);
    int* deg      = (int*)alloc((size_t)n * 4);
    int* rowstart = (int*)alloc((size_t)n * 4);
    int* cursor   = (int*)alloc((size_t)n * 4);
    int* partial  = (int*)alloc(512 * 4);
    int* chunkoff = (int*)alloc(512 * 4);
    int* csrc     = (int*)alloc((size_t)ne * 4);

    int nb = (n + 255) / 256;
    hipMemsetAsync(deg, 0, (size_t)n * 4, stream);
    deg_count<<<(ne + 255) / 256, 256, 0, stream>>>(dstv, deg, ne);
    scan_partial<<<nb, 256, 0, stream>>>(deg, partial, n);
    scan_offsets<<<1, 512, 0, stream>>>(partial, chunkoff, nb);
    scan_final<<<nb, 256, 0, stream>>>(deg, chunkoff, rowstart, cursor, n);
    csr_scatter<<<(ne + 255) / 256, 256, 0, stream>>>(srcv, dstv, cursor, csrc, ne);
    gemm1<<<(n + 31) / 32, 256, 0, stream>>>(x, W1, as1, ad1, h1, es1, ed1, n);
    agg1<<<(n + 3) / 4, 256, 0, stream>>>(h1, es1, ed1, b1, rowstart, deg, csrc, hr, n);
    gemm2<<<(n + 15) / 16, 256, 0, stream>>>(hr, W2, as2, ad2, h2, es2, ed2, n);
    agg2<<<(n + 3) / 4, 256, 0, stream>>>(h2, es2, ed2, b2, rowstart, deg, csrc, (float*)d_out, n);
}

// Round 2
// 410.413 us; speedup vs baseline: 1.3803x; 1.3803x over previous
//
#include <hip/hip_runtime.h>

#define NEG_SLOPE 0.2f

static __device__ __forceinline__ float lrelu(float x) { return x > 0.f ? x : NEG_SLOPE * x; }

static __device__ __forceinline__ float b2f(unsigned short u) {
    union { unsigned int i; float f; } c; c.i = ((unsigned int)u) << 16; return c.f;
}
static __device__ __forceinline__ unsigned short f2b(float f) {
    union { float f; unsigned int i; } c; c.f = f;
    unsigned int r = c.i + 0x7fff + ((c.i >> 16) & 1);   // RNE
    return (unsigned short)(r >> 16);
}

// ---------------- CSR build ----------------

__global__ void deg_count(const int* __restrict__ dst, int* __restrict__ deg, int ne) {
    int i = blockIdx.x * 256 + threadIdx.x;
    if (i < ne) atomicAdd(&deg[dst[i]], 1);
}

__global__ void scan_partial(const int* __restrict__ deg, int* __restrict__ partial, int n) {
    int i = blockIdx.x * 256 + threadIdx.x;
    int v = (i < n) ? deg[i] : 0;
    #pragma unroll
    for (int off = 32; off >= 1; off >>= 1) v += __shfl_xor(v, off, 64);
    __shared__ int ws[4];
    int lane = threadIdx.x & 63, wid = threadIdx.x >> 6;
    if (lane == 0) ws[wid] = v;
    __syncthreads();
    if (threadIdx.x == 0) partial[blockIdx.x] = ws[0] + ws[1] + ws[2] + ws[3];
}

__global__ void scan_offsets(const int* __restrict__ partial, int* __restrict__ chunkoff, int nb) {
    int t = threadIdx.x;
    int v = (t < nb) ? partial[t] : 0;
    int lane = t & 63, wid = t >> 6;
    int incl = v;
    #pragma unroll
    for (int off = 1; off < 64; off <<= 1) {
        int u = __shfl_up(incl, off, 64);
        if (lane >= off) incl += u;
    }
    __shared__ int ws[8];
    if (lane == 63) ws[wid] = incl;
    __syncthreads();
    if (t < 8) {
        int s = ws[t];
        #pragma unroll
        for (int off = 1; off < 8; off <<= 1) {
            int u = __shfl_up(s, off, 64);
            if (t >= off) s += u;
        }
        ws[t] = s;
    }
    __syncthreads();
    int excl = incl - v + (wid > 0 ? ws[wid - 1] : 0);
    if (t < nb) chunkoff[t] = excl;
}

__global__ void scan_final(const int* __restrict__ deg, const int* __restrict__ chunkoff,
                           int* __restrict__ rowstart, int* __restrict__ cursor, int n) {
    int i = blockIdx.x * 256 + threadIdx.x;
    int v = (i < n) ? deg[i] : 0;
    int lane = threadIdx.x & 63, wid = threadIdx.x >> 6;
    int incl = v;
    #pragma unroll
    for (int off = 1; off < 64; off <<= 1) {
        int u = __shfl_up(incl, off, 64);
        if (lane >= off) incl += u;
    }
    __shared__ int ws[4];
    if (lane == 63) ws[wid] = incl;
    __syncthreads();
    if (threadIdx.x < 4) {
        int s = ws[threadIdx.x];
        #pragma unroll
        for (int off = 1; off < 4; off <<= 1) {
            int u = __shfl_up(s, off, 64);
            if (threadIdx.x >= off) s += u;
        }
        ws[threadIdx.x] = s;
    }
    __syncthreads();
    int excl = incl - v + (wid > 0 ? ws[wid - 1] : 0) + chunkoff[blockIdx.x];
    if (i < n) { rowstart[i] = excl; cursor[i] = excl; }
}

__global__ void csr_scatter(const int* __restrict__ src, const int* __restrict__ dst,
                            int* __restrict__ cursor, int* __restrict__ csrc, int ne) {
    int i = blockIdx.x * 256 + threadIdx.x;
    if (i < ne) {
        int pos = atomicAdd(&cursor[dst[i]], 1);
        csrc[pos] = src[i];
    }
}

// ---------------- Layer 1: h1 = x @ W1, bf16 out; W1 column in 128 VGPRs ----------------

__global__ __launch_bounds__(256) void gemm1(const float* __restrict__ x, const float* __restrict__ W1,
                                             const float* __restrict__ asrc, const float* __restrict__ adst,
                                             unsigned short* __restrict__ h, float* __restrict__ es,
                                             float* __restrict__ ed, int n) {
    __shared__ float xl[32][128];   // 16 KB
    int tid = threadIdx.x;
    int lane = tid & 63, wid = tid >> 6;
    // each lane keeps its W1 column (HID col = lane) in registers
    float w[128];
    #pragma unroll
    for (int k = 0; k < 128; ++k) w[k] = W1[k * 64 + lane];
    int base = blockIdx.x * 32;
    for (int i = tid; i < 32 * 32; i += 256) {           // 32 rows x 32 float4
        int r = i >> 5, c4 = i & 31;
        int nidx = base + r;
        float4 v = make_float4(0.f, 0.f, 0.f, 0.f);
        if (nidx < n) v = *(const float4*)&x[(size_t)nidx * 128 + c4 * 4];
        *(float4*)&xl[r][c4 * 4] = v;
    }
    __syncthreads();
    float as_ = asrc[lane], ad_ = adst[lane];
    for (int r = wid; r < 32; r += 4) {
        int nidx = base + r;
        if (nidx >= n) break;
        float acc = 0.f;
        #pragma unroll
        for (int kk = 0; kk < 32; ++kk) {
            float4 xv = *(const float4*)&xl[r][kk * 4];
            acc = fmaf(xv.x, w[4 * kk + 0], acc);
            acc = fmaf(xv.y, w[4 * kk + 1], acc);
            acc = fmaf(xv.z, w[4 * kk + 2], acc);
            acc = fmaf(xv.w, w[4 * kk + 3], acc);
        }
        h[(size_t)nidx * 64 + lane] = f2b(acc);
        float s = acc * as_, d = acc * ad_;
        #pragma unroll
        for (int off = 32; off >= 1; off >>= 1) {
            s += __shfl_xor(s, off, 64);
            d += __shfl_xor(d, off, 64);
        }
        if (lane == 0) { es[nidx] = s; ed[nidx] = d; }
    }
}

// ---------------- Layer 1 aggregation: wave/node, ILP-4 online softmax, bf16 gathers ----------------

__global__ __launch_bounds__(256) void agg1(const unsigned short* __restrict__ h, const float* __restrict__ es,
                                            const float* __restrict__ ed, const float* __restrict__ b1,
                                            const int* __restrict__ rowstart, const int* __restrict__ deg,
                                            const int* __restrict__ csrc, unsigned short* __restrict__ out, int n) {
    int wid = threadIdx.x >> 6, lane = threadIdx.x & 63;
    int node = blockIdx.x * 4 + wid;
    if (node >= n) return;
    float edn = ed[node];
    float m = lrelu(es[node] + edn);    // self-loop
    float z = 1.0f;
    float acc = b2f(h[(size_t)node * 64 + lane]);
    int s0 = rowstart[node], cnt = deg[node];
    int i = 0;
    for (; i + 4 <= cnt; i += 4) {
        int sA = csrc[s0 + i], sB = csrc[s0 + i + 1], sC = csrc[s0 + i + 2], sD = csrc[s0 + i + 3];
        float eA = lrelu(es[sA] + edn), eB = lrelu(es[sB] + edn);
        float eC = lrelu(es[sC] + edn), eD = lrelu(es[sD] + edn);
        float hA = b2f(h[(size_t)sA * 64 + lane]);
        float hB = b2f(h[(size_t)sB * 64 + lane]);
        float hC = b2f(h[(size_t)sC * 64 + lane]);
        float hD = b2f(h[(size_t)sD * 64 + lane]);
        float mb = fmaxf(fmaxf(eA, eB), fmaxf(eC, eD));
        if (mb <= m) {                       // wave-uniform (e, m are wave-uniform)
            float wA = __expf(eA - m), wB = __expf(eB - m);
            float wC = __expf(eC - m), wD = __expf(eD - m);
            z += (wA + wB) + (wC + wD);
            acc = fmaf(hA, wA, acc);
            acc = fmaf(hB, wB, acc);
            acc = fmaf(hC, wC, acc);
            acc = fmaf(hD, wD, acc);
        } else {
            float c = __expf(m - mb);
            float wA = __expf(eA - mb), wB = __expf(eB - mb);
            float wC = __expf(eC - mb), wD = __expf(eD - mb);
            z = fmaf(z, c, (wA + wB) + (wC + wD));
            acc = acc * c;
            acc = fmaf(hA, wA, acc);
            acc = fmaf(hB, wB, acc);
            acc = fmaf(hC, wC, acc);
            acc = fmaf(hD, wD, acc);
            m = mb;
        }
    }
    for (; i < cnt; ++i) {
        int s = csrc[s0 + i];
        float e = lrelu(es[s] + edn);
        float hv = b2f(h[(size_t)s * 64 + lane]);
        if (e <= m) {
            float w_ = __expf(e - m);
            z += w_;
            acc = fmaf(hv, w_, acc);
        } else {
            float c = __expf(m - e);
            z = fmaf(z, c, 1.0f);
            acc = fmaf(acc, c, hv);
            m = e;
        }
    }
    float o = acc / z + b1[lane];
    out[(size_t)node * 64 + lane] = f2b(o > 0.f ? o : 0.f);   // fused ReLU, bf16
}

// ---------------- Layer 2: h2 = hr @ W2, bf16 in/out; W2 column in 64 VGPRs ----------------

__global__ __launch_bounds__(256) void gemm2(const unsigned short* __restrict__ hin, const float* __restrict__ W2,
                                             const float* __restrict__ asrc, const float* __restrict__ adst,
                                             unsigned short* __restrict__ h2, float* __restrict__ es,
                                             float* __restrict__ ed, int n) {
    __shared__ float xl[16][64];   // 4 KB
    int tid = threadIdx.x;
    int lane = tid & 63, wid = tid >> 6;
    int sub = lane >> 4, j = lane & 15;
    float w2[64];
    #pragma unroll
    for (int k = 0; k < 64; ++k) w2[k] = W2[k * 16 + j];
    int base = blockIdx.x * 16;
    for (int i = tid; i < 16 * 64; i += 256) {
        int r = i >> 6, c = i & 63;
        int nidx = base + r;
        xl[r][c] = (nidx < n) ? b2f(hin[(size_t)nidx * 64 + c]) : 0.f;
    }
    __syncthreads();
    int r = wid * 4 + sub;
    int nidx = base + r;
    if (nidx < n) {
        float acc = 0.f;
        #pragma unroll
        for (int kk = 0; kk < 16; ++kk) {
            float4 xv = *(const float4*)&xl[r][kk * 4];
            acc = fmaf(xv.x, w2[4 * kk + 0], acc);
            acc = fmaf(xv.y, w2[4 * kk + 1], acc);
            acc = fmaf(xv.z, w2[4 * kk + 2], acc);
            acc = fmaf(xv.w, w2[4 * kk + 3], acc);
        }
        h2[(size_t)nidx * 16 + j] = f2b(acc);
        float s = acc * asrc[j], d = acc * adst[j];
        #pragma unroll
        for (int off = 8; off >= 1; off >>= 1) {
            s += __shfl_xor(s, off, 64);
            d += __shfl_xor(d, off, 64);
        }
        if (j == 0) { es[nidx] = s; ed[nidx] = d; }
    }
}

// ---------------- Layer 2 aggregation + bias + log_softmax ----------------

__global__ __launch_bounds__(256) void agg2(const unsigned short* __restrict__ h, const float* __restrict__ es,
                                            const float* __restrict__ ed, const float* __restrict__ b2,
                                            const int* __restrict__ rowstart, const int* __restrict__ deg,
                                            const int* __restrict__ csrc, float* __restrict__ out, int n) {
    int wid = threadIdx.x >> 6, lane = threadIdx.x & 63;
    int node = blockIdx.x * 4 + wid;
    if (node >= n) return;
    int sub = lane >> 4, j = lane & 15;
    float edn = ed[node];
    int s0 = rowstart[node], cnt = deg[node];
    int total = cnt + 1;                       // virtual edge 0 = self-loop
    float m = -1e30f, z = 0.f, acc = 0.f;
    for (int i = sub; i < total; i += 4) {
        int s = (i == 0) ? node : csrc[s0 + i - 1];
        float e = lrelu(es[s] + edn);
        float hv = b2f(h[(size_t)s * 16 + j]);
        if (e <= m) {
            float w_ = __expf(e - m);
            z += w_;
            acc = fmaf(hv, w_, acc);
        } else {
            float c = __expf(m - e);
            z = fmaf(z, c, 1.0f);
            acc = fmaf(acc, c, hv);
            m = e;
        }
    }
    #pragma unroll
    for (int off = 16; off <= 32; off <<= 1) {
        float mo = __shfl_xor(m, off, 64);
        float zo = __shfl_xor(z, off, 64);
        float ao = __shfl_xor(acc, off, 64);
        float mn = fmaxf(m, mo);
        float c0 = __expf(m - mn), c1 = __expf(mo - mn);
        z = z * c0 + zo * c1;
        acc = acc * c0 + ao * c1;
        m = mn;
    }
    float val = acc / z + b2[j];
    float mx = val;
    #pragma unroll
    for (int off = 8; off >= 1; off >>= 1) mx = fmaxf(mx, __shfl_xor(mx, off, 64));
    float ex = __expf(val - mx);
    float se = ex;
    #pragma unroll
    for (int off = 8; off >= 1; off >>= 1) se += __shfl_xor(se, off, 64);
    float res = val - mx - __logf(se);
    if (sub == 0) out[(size_t)node * 16 + j] = res;
}

// ---------------- launch ----------------

extern "C" void kernel_launch(void* const* d_in, const int* in_sizes, int n_in,
                              void* d_out, int out_size, void* d_ws, size_t ws_size,
                              hipStream_t stream) {
    const float* x   = (const float*)d_in[0];
    const int*   ei  = (const int*)d_in[1];
    const float* W1  = (const float*)d_in[2];
    const float* as1 = (const float*)d_in[3];
    const float* ad1 = (const float*)d_in[4];
    const float* b1  = (const float*)d_in[5];
    const float* W2  = (const float*)d_in[6];
    const float* as2 = (const float*)d_in[7];
    const float* ad2 = (const float*)d_in[8];
    const float* b2  = (const float*)d_in[9];
    int n  = in_sizes[0] / 128;
    int ne = in_sizes[1] / 2;
    const int* srcv = ei;
    const int* dstv = ei + ne;

    char* ws = (char*)d_ws;
    size_t off = 0;
    auto alloc = [&](size_t bytes) -> void* {
        void* p = ws + off;
        off = (off + bytes + 255) & ~(size_t)255;
        return p;
    };
    unsigned short* h1 = (unsigned short*)alloc((size_t)n * 64 * 2);
    unsigned short* hr = (unsigned short*)alloc((size_t)n * 64 * 2);
    unsigned short* h2 = (unsigned short*)alloc((size_t)n * 16 * 2);
    float* es1  = (float*)alloc((size_t)n * 4);
    float* ed1  = (float*)alloc((size_t)n * 4);
    float* es2  = (float*)alloc((size_t)n * 4);
    float* ed2  = (float*)alloc((size_t)n * 4);
    int* deg      = (int*)alloc((size_t)n * 4);
    int* rowstart = (int*)alloc((size_t)n * 4);
    int* cursor   = (int*)alloc((size_t)n * 4);
    int* partial  = (int*)alloc(512 * 4);
    int* chunkoff = (int*)alloc(512 * 4);
    int* csrc     = (int*)alloc((size_t)ne * 4);

    int nb = (n + 255) / 256;
    hipMemsetAsync(deg, 0, (size_t)n * 4, stream);
    deg_count<<<(ne + 255) / 256, 256, 0, stream>>>(dstv, deg, ne);
    scan_partial<<<nb, 256, 0, stream>>>(deg, partial, n);
    scan_offsets<<<1, 512, 0, stream>>>(partial, chunkoff, nb);
    scan_final<<<nb, 256, 0, stream>>>(deg, chunkoff, rowstart, cursor, n);
    csr_scatter<<<(ne + 255) / 256, 256, 0, stream>>>(srcv, dstv, cursor, csrc, ne);
    gemm1<<<(n + 31) / 32, 256, 0, stream>>>(x, W1, as1, ad1, h1, es1, ed1, n);
    agg1<<<(n + 3) / 4, 256, 0, stream>>>(h1, es1, ed1, b1, rowstart, deg, csrc, hr, n);
    gemm2<<<(n + 15) / 16, 256, 0, stream>>>(hr, W2, as2, ad2, h2, es2, ed2, n);
    agg2<<<(n + 3) / 4, 256, 0, stream>>>(h2, es2, ed2, b2, rowstart, deg, csrc, (float*)d_out, n);
}

// Round 3
// 276.816 us; speedup vs baseline: 2.0464x; 1.4826x over previous
//
#include <hip/hip_runtime.h>

#define NEG_SLOPE 0.2f
#define NBUCK 1024          // coarse buckets, 128 nodes each (supports n <= 131072)

static __device__ __forceinline__ float lrelu(float x) { return x > 0.f ? x : NEG_SLOPE * x; }

static __device__ __forceinline__ float b2f(unsigned short u) {
    union { unsigned int i; float f; } c; c.i = ((unsigned int)u) << 16; return c.f;
}
static __device__ __forceinline__ unsigned short f2b(float f) {
    union { float f; unsigned int i; } c; c.f = f;
    unsigned int r = c.i + 0x7fff + ((c.i >> 16) & 1);   // RNE
    return (unsigned short)(r >> 16);
}

// ---------------- CSR build: two-level bucket sort ----------------

__global__ __launch_bounds__(256) void bucket_count(const int* __restrict__ dst, int* __restrict__ gcount,
                                                    int ne, int epb) {
    __shared__ int cnt[NBUCK];
    int tid = threadIdx.x;
    for (int i = tid; i < NBUCK; i += 256) cnt[i] = 0;
    __syncthreads();
    int lo = blockIdx.x * epb;
    int hi = min(ne, lo + epb);
    for (int i = lo + tid; i < hi; i += 256) atomicAdd(&cnt[dst[i] >> 7], 1);
    __syncthreads();
    for (int i = tid; i < NBUCK; i += 256) if (cnt[i]) atomicAdd(&gcount[i], cnt[i]);
}

// single block, 1024 threads: exclusive scan of bucket counts -> bucketStart, init cursor
__global__ __launch_bounds__(1024) void bucket_scan(const int* __restrict__ gcount, int* __restrict__ bstart,
                                                    int* __restrict__ gcur) {
    int t = threadIdx.x;
    int v = gcount[t];
    int lane = t & 63, wid = t >> 6;     // 16 waves
    int incl = v;
    #pragma unroll
    for (int off = 1; off < 64; off <<= 1) {
        int u = __shfl_up(incl, off, 64);
        if (lane >= off) incl += u;
    }
    __shared__ int ws[16];
    if (lane == 63) ws[wid] = incl;
    __syncthreads();
    if (t < 16) {
        int s = ws[t];
        #pragma unroll
        for (int off = 1; off < 16; off <<= 1) {
            int u = __shfl_up(s, off, 64);
            if (t >= off) s += u;
        }
        ws[t] = s;
    }
    __syncthreads();
    int excl = incl - v + (wid > 0 ? ws[wid - 1] : 0);
    bstart[t] = excl;
    gcur[t] = excl;
    if (t == 1023) bstart[NBUCK] = excl + v;   // == ne
}

// per block: LDS count -> reserve contiguous global sub-range per bucket -> dense write of packed edges
__global__ __launch_bounds__(256) void bucket_place(const int* __restrict__ src, const int* __restrict__ dst,
                                                    int* __restrict__ gcur, unsigned int* __restrict__ gstage,
                                                    int ne, int epb) {
    __shared__ int cnt[NBUCK];
    __shared__ int cur[NBUCK];
    int tid = threadIdx.x;
    for (int i = tid; i < NBUCK; i += 256) cnt[i] = 0;
    __syncthreads();
    int lo = blockIdx.x * epb;
    int hi = min(ne, lo + epb);
    for (int i = lo + tid; i < hi; i += 256) atomicAdd(&cnt[dst[i] >> 7], 1);
    __syncthreads();
    for (int b = tid; b < NBUCK; b += 256) {
        int c = cnt[b];
        cur[b] = c ? atomicAdd(&gcur[b], c) : 0;
    }
    __syncthreads();
    for (int i = lo + tid; i < hi; i += 256) {
        int d = dst[i];
        int b = d >> 7;
        int p = atomicAdd(&cur[b], 1);               // cur holds GLOBAL base
        gstage[p] = (unsigned int)src[i] | (((unsigned int)(d & 127)) << 17);
    }
}

// one block per bucket: node histogram -> rowstart/deg, then in-bucket scatter to exact CSR slots
__global__ __launch_bounds__(256) void bucket_csr(const unsigned int* __restrict__ gstage,
                                                  const int* __restrict__ bstart,
                                                  int* __restrict__ rowstart, int* __restrict__ deg,
                                                  int* __restrict__ csrc, int n) {
    int b = blockIdx.x;
    int nodebase = b << 7;
    if (nodebase >= n) return;
    int bs = bstart[b];
    int cntb = bstart[b + 1] - bs;
    __shared__ int hist[128], cur[128], ws[2];
    int tid = threadIdx.x;
    if (tid < 128) hist[tid] = 0;
    __syncthreads();
    for (int i = tid; i < cntb; i += 256) atomicAdd(&hist[(gstage[bs + i] >> 17) & 127], 1);
    __syncthreads();
    int v = 0, incl = 0;
    int lane = tid & 63, wid = tid >> 6;
    if (tid < 128) {
        v = hist[tid];
        incl = v;
        #pragma unroll
        for (int off = 1; off < 64; off <<= 1) {
            int u = __shfl_up(incl, off, 64);
            if (lane >= off) incl += u;
        }
        if (lane == 63) ws[wid] = incl;
    }
    __syncthreads();
    if (tid < 128) {
        int excl = incl - v + (wid == 1 ? ws[0] : 0);
        int node = nodebase + tid;
        if (node < n) { rowstart[node] = bs + excl; deg[node] = v; }
        cur[tid] = excl;
    }
    __syncthreads();
    for (int i = tid; i < cntb; i += 256) {
        unsigned int e = gstage[bs + i];
        int ld = (e >> 17) & 127;
        int p = atomicAdd(&cur[ld], 1);
        csrc[bs + p] = (int)(e & 0x1FFFFu);
    }
}

// ---------------- Layer 1: h1 = x @ W1, bf16 out; W1 column in 128 VGPRs ----------------

__global__ __launch_bounds__(256) void gemm1(const float* __restrict__ x, const float* __restrict__ W1,
                                             const float* __restrict__ asrc, const float* __restrict__ adst,
                                             unsigned short* __restrict__ h, float* __restrict__ es,
                                             float* __restrict__ ed, int n) {
    __shared__ float xl[32][128];   // 16 KB
    int tid = threadIdx.x;
    int lane = tid & 63, wid = tid >> 6;
    float w[128];
    #pragma unroll
    for (int k = 0; k < 128; ++k) w[k] = W1[k * 64 + lane];
    int base = blockIdx.x * 32;
    for (int i = tid; i < 32 * 32; i += 256) {
        int r = i >> 5, c4 = i & 31;
        int nidx = base + r;
        float4 v = make_float4(0.f, 0.f, 0.f, 0.f);
        if (nidx < n) v = *(const float4*)&x[(size_t)nidx * 128 + c4 * 4];
        *(float4*)&xl[r][c4 * 4] = v;
    }
    __syncthreads();
    float as_ = asrc[lane], ad_ = adst[lane];
    for (int r = wid; r < 32; r += 4) {
        int nidx = base + r;
        if (nidx >= n) break;
        float acc = 0.f;
        #pragma unroll
        for (int kk = 0; kk < 32; ++kk) {
            float4 xv = *(const float4*)&xl[r][kk * 4];
            acc = fmaf(xv.x, w[4 * kk + 0], acc);
            acc = fmaf(xv.y, w[4 * kk + 1], acc);
            acc = fmaf(xv.z, w[4 * kk + 2], acc);
            acc = fmaf(xv.w, w[4 * kk + 3], acc);
        }
        h[(size_t)nidx * 64 + lane] = f2b(acc);
        float s = acc * as_, d = acc * ad_;
        #pragma unroll
        for (int off = 32; off >= 1; off >>= 1) {
            s += __shfl_xor(s, off, 64);
            d += __shfl_xor(d, off, 64);
        }
        if (lane == 0) { es[nidx] = s; ed[nidx] = d; }
    }
}

// ---------------- Layer 1 aggregation: wave/node, ILP-4 online softmax, bf16 gathers ----------------

__global__ __launch_bounds__(256) void agg1(const unsigned short* __restrict__ h, const float* __restrict__ es,
                                            const float* __restrict__ ed, const float* __restrict__ b1,
                                            const int* __restrict__ rowstart, const int* __restrict__ deg,
                                            const int* __restrict__ csrc, unsigned short* __restrict__ out, int n) {
    int wid = threadIdx.x >> 6, lane = threadIdx.x & 63;
    int node = blockIdx.x * 4 + wid;
    if (node >= n) return;
    float edn = ed[node];
    float m = lrelu(es[node] + edn);    // self-loop
    float z = 1.0f;
    float acc = b2f(h[(size_t)node * 64 + lane]);
    int s0 = rowstart[node], cnt = deg[node];
    int i = 0;
    for (; i + 4 <= cnt; i += 4) {
        int sA = csrc[s0 + i], sB = csrc[s0 + i + 1], sC = csrc[s0 + i + 2], sD = csrc[s0 + i + 3];
        float eA = lrelu(es[sA] + edn), eB = lrelu(es[sB] + edn);
        float eC = lrelu(es[sC] + edn), eD = lrelu(es[sD] + edn);
        float hA = b2f(h[(size_t)sA * 64 + lane]);
        float hB = b2f(h[(size_t)sB * 64 + lane]);
        float hC = b2f(h[(size_t)sC * 64 + lane]);
        float hD = b2f(h[(size_t)sD * 64 + lane]);
        float mb = fmaxf(fmaxf(eA, eB), fmaxf(eC, eD));
        if (mb <= m) {                       // wave-uniform
            float wA = __expf(eA - m), wB = __expf(eB - m);
            float wC = __expf(eC - m), wD = __expf(eD - m);
            z += (wA + wB) + (wC + wD);
            acc = fmaf(hA, wA, acc);
            acc = fmaf(hB, wB, acc);
            acc = fmaf(hC, wC, acc);
            acc = fmaf(hD, wD, acc);
        } else {
            float c = __expf(m - mb);
            float wA = __expf(eA - mb), wB = __expf(eB - mb);
            float wC = __expf(eC - mb), wD = __expf(eD - mb);
            z = fmaf(z, c, (wA + wB) + (wC + wD));
            acc = acc * c;
            acc = fmaf(hA, wA, acc);
            acc = fmaf(hB, wB, acc);
            acc = fmaf(hC, wC, acc);
            acc = fmaf(hD, wD, acc);
            m = mb;
        }
    }
    for (; i < cnt; ++i) {
        int s = csrc[s0 + i];
        float e = lrelu(es[s] + edn);
        float hv = b2f(h[(size_t)s * 64 + lane]);
        if (e <= m) {
            float w_ = __expf(e - m);
            z += w_;
            acc = fmaf(hv, w_, acc);
        } else {
            float c = __expf(m - e);
            z = fmaf(z, c, 1.0f);
            acc = fmaf(acc, c, hv);
            m = e;
        }
    }
    float o = acc / z + b1[lane];
    out[(size_t)node * 64 + lane] = f2b(o > 0.f ? o : 0.f);   // fused ReLU, bf16
}

// ---------------- Layer 2: h2 = hr @ W2, bf16 in/out; W2 column in 64 VGPRs ----------------

__global__ __launch_bounds__(256) void gemm2(const unsigned short* __restrict__ hin, const float* __restrict__ W2,
                                             const float* __restrict__ asrc, const float* __restrict__ adst,
                                             unsigned short* __restrict__ h2, float* __restrict__ es,
                                             float* __restrict__ ed, int n) {
    __shared__ float xl[16][64];   // 4 KB
    int tid = threadIdx.x;
    int lane = tid & 63, wid = tid >> 6;
    int sub = lane >> 4, j = lane & 15;
    float w2[64];
    #pragma unroll
    for (int k = 0; k < 64; ++k) w2[k] = W2[k * 16 + j];
    int base = blockIdx.x * 16;
    for (int i = tid; i < 16 * 64; i += 256) {
        int r = i >> 6, c = i & 63;
        int nidx = base + r;
        xl[r][c] = (nidx < n) ? b2f(hin[(size_t)nidx * 64 + c]) : 0.f;
    }
    __syncthreads();
    int r = wid * 4 + sub;
    int nidx = base + r;
    if (nidx < n) {
        float acc = 0.f;
        #pragma unroll
        for (int kk = 0; kk < 16; ++kk) {
            float4 xv = *(const float4*)&xl[r][kk * 4];
            acc = fmaf(xv.x, w2[4 * kk + 0], acc);
            acc = fmaf(xv.y, w2[4 * kk + 1], acc);
            acc = fmaf(xv.z, w2[4 * kk + 2], acc);
            acc = fmaf(xv.w, w2[4 * kk + 3], acc);
        }
        h2[(size_t)nidx * 16 + j] = f2b(acc);
        float s = acc * asrc[j], d = acc * adst[j];
        #pragma unroll
        for (int off = 8; off >= 1; off >>= 1) {
            s += __shfl_xor(s, off, 64);
            d += __shfl_xor(d, off, 64);
        }
        if (j == 0) { es[nidx] = s; ed[nidx] = d; }
    }
}

// ---------------- Layer 2 aggregation + bias + log_softmax ----------------

__global__ __launch_bounds__(256) void agg2(const unsigned short* __restrict__ h, const float* __restrict__ es,
                                            const float* __restrict__ ed, const float* __restrict__ b2,
                                            const int* __restrict__ rowstart, const int* __restrict__ deg,
                                            const int* __restrict__ csrc, float* __restrict__ out, int n) {
    int wid = threadIdx.x >> 6, lane = threadIdx.x & 63;
    int node = blockIdx.x * 4 + wid;
    if (node >= n) return;
    int sub = lane >> 4, j = lane & 15;
    float edn = ed[node];
    int s0 = rowstart[node], cnt = deg[node];
    int total = cnt + 1;                       // virtual edge 0 = self-loop
    float m = -1e30f, z = 0.f, acc = 0.f;
    for (int i = sub; i < total; i += 4) {
        int s = (i == 0) ? node : csrc[s0 + i - 1];
        float e = lrelu(es[s] + edn);
        float hv = b2f(h[(size_t)s * 16 + j]);
        if (e <= m) {
            float w_ = __expf(e - m);
            z += w_;
            acc = fmaf(hv, w_, acc);
        } else {
            float c = __expf(m - e);
            z = fmaf(z, c, 1.0f);
            acc = fmaf(acc, c, hv);
            m = e;
        }
    }
    #pragma unroll
    for (int off = 16; off <= 32; off <<= 1) {
        float mo = __shfl_xor(m, off, 64);
        float zo = __shfl_xor(z, off, 64);
        float ao = __shfl_xor(acc, off, 64);
        float mn = fmaxf(m, mo);
        float c0 = __expf(m - mn), c1 = __expf(mo - mn);
        z = z * c0 + zo * c1;
        acc = acc * c0 + ao * c1;
        m = mn;
    }
    float val = acc / z + b2[j];
    float mx = val;
    #pragma unroll
    for (int off = 8; off >= 1; off >>= 1) mx = fmaxf(mx, __shfl_xor(mx, off, 64));
    float ex = __expf(val - mx);
    float se = ex;
    #pragma unroll
    for (int off = 8; off >= 1; off >>= 1) se += __shfl_xor(se, off, 64);
    float res = val - mx - __logf(se);
    if (sub == 0) out[(size_t)node * 16 + j] = res;
}

// ---------------- launch ----------------

extern "C" void kernel_launch(void* const* d_in, const int* in_sizes, int n_in,
                              void* d_out, int out_size, void* d_ws, size_t ws_size,
                              hipStream_t stream) {
    const float* x   = (const float*)d_in[0];
    const int*   ei  = (const int*)d_in[1];
    const float* W1  = (const float*)d_in[2];
    const float* as1 = (const float*)d_in[3];
    const float* ad1 = (const float*)d_in[4];
    const float* b1  = (const float*)d_in[5];
    const float* W2  = (const float*)d_in[6];
    const float* as2 = (const float*)d_in[7];
    const float* ad2 = (const float*)d_in[8];
    const float* b2  = (const float*)d_in[9];
    int n  = in_sizes[0] / 128;
    int ne = in_sizes[1] / 2;
    const int* srcv = ei;
    const int* dstv = ei + ne;

    char* ws = (char*)d_ws;
    size_t off = 0;
    auto alloc = [&](size_t bytes) -> void* {
        void* p = ws + off;
        off = (off + bytes + 255) & ~(size_t)255;
        return p;
    };
    unsigned short* h1 = (unsigned short*)alloc((size_t)n * 64 * 2);
    unsigned short* hr = (unsigned short*)alloc((size_t)n * 64 * 2);
    unsigned short* h2 = (unsigned short*)alloc((size_t)n * 16 * 2);
    float* es1  = (float*)alloc((size_t)n * 4);
    float* ed1  = (float*)alloc((size_t)n * 4);
    float* es2  = (float*)alloc((size_t)n * 4);
    float* ed2  = (float*)alloc((size_t)n * 4);
    int* deg      = (int*)alloc((size_t)n * 4);
    int* rowstart = (int*)alloc((size_t)n * 4);
    int* bcount   = (int*)alloc((size_t)NBUCK * 4);
    int* bstart   = (int*)alloc((size_t)(NBUCK + 1) * 4);
    int* gcur     = (int*)alloc((size_t)NBUCK * 4);
    unsigned int* gstage = (unsigned int*)alloc((size_t)ne * 4);
    int* csrc     = (int*)alloc((size_t)ne * 4);

    int nblk = 512;
    int epb = (ne + nblk - 1) / nblk;
    hipMemsetAsync(bcount, 0, (size_t)NBUCK * 4, stream);
    bucket_count<<<nblk, 256, 0, stream>>>(dstv, bcount, ne, epb);
    bucket_scan<<<1, 1024, 0, stream>>>(bcount, bstart, gcur);
    bucket_place<<<nblk, 256, 0, stream>>>(srcv, dstv, gcur, gstage, ne, epb);
    bucket_csr<<<NBUCK, 256, 0, stream>>>(gstage, bstart, rowstart, deg, csrc, n);
    gemm1<<<(n + 31) / 32, 256, 0, stream>>>(x, W1, as1, ad1, h1, es1, ed1, n);
    agg1<<<(n + 3) / 4, 256, 0, stream>>>(h1, es1, ed1, b1, rowstart, deg, csrc, hr, n);
    gemm2<<<(n + 15) / 16, 256, 0, stream>>>(hr, W2, as2, ad2, h2, es2, ed2, n);
    agg2<<<(n + 3) / 4, 256, 0, stream>>>(h2, es2, ed2, b2, rowstart, deg, csrc, (float*)d_out, n);
}